// Round 2
// baseline (2224.051 us; speedup 1.0000x reference)
//
#include <hip/hip_runtime.h>

#define TOKENS 32768
#define DIMD 384
#define HID 1536
#define NE 4
#define NPAIR 6
#define BM 64
#define BH 128
#define TILES_PER_PAIR (TOKENS / BM)  // 512

typedef __bf16 bf16;
typedef bf16 bf16x8 __attribute__((ext_vector_type(8)));
typedef float f32x4 __attribute__((ext_vector_type(4)));
typedef unsigned int u32x4 __attribute__((ext_vector_type(4)));

__device__ __forceinline__ unsigned short f2bf(float f) {
  unsigned u = __builtin_bit_cast(unsigned, f);
  u += 0x7fffu + ((u >> 16) & 1u);
  return (unsigned short)(u >> 16);
}
__device__ __forceinline__ unsigned pk2(float lo, float hi) {
  return (unsigned)f2bf(lo) | ((unsigned)f2bf(hi) << 16);
}
// tanh-form gelu, max |err| vs erf-gelu ~4e-4 (threshold 5.7e-2)
__device__ __forceinline__ float gelu_f(float v) {
  float u2 = 1.5957691216057308f * v * (1.0f + 0.044715f * v * v);
  return v / (1.0f + __expf(-u2));
}

// ---------------- transpose + fp32->bf16 convert ----------------
__global__ __launch_bounds__(256) void transpose_cvt_kernel(
    const float* __restrict__ src, unsigned short* __restrict__ dst,
    int R, int C) {
  __shared__ float tile[32][33];
  int e = blockIdx.z;
  const float* s = src + (size_t)e * R * C;
  unsigned short* d = dst + (size_t)e * R * C;
  int c0 = blockIdx.x * 32, r0 = blockIdx.y * 32;
  int tx = threadIdx.x, ty = threadIdx.y;  // (32, 8)
#pragma unroll
  for (int i = 0; i < 32; i += 8)
    tile[ty + i][tx] = s[(size_t)(r0 + ty + i) * C + (c0 + tx)];
  __syncthreads();
#pragma unroll
  for (int i = 0; i < 32; i += 8)
    d[(size_t)(c0 + ty + i) * R + (r0 + tx)] = f2bf(tile[tx][ty + i]);
}

// ---------------- zero counters ----------------
__global__ void zero_cnt_kernel(int* cnt) {
  if (threadIdx.x < 8) cnt[threadIdx.x] = 0;
}

// ---------------- gating: softmax, top-2, renorm, pair-id ----------------
__global__ __launch_bounds__(256) void gate_kernel(
    const float* __restrict__ x, const float* __restrict__ gw,
    const float* __restrict__ gb, float* __restrict__ wgt,
    unsigned char* __restrict__ pid) {
  int lane = threadIdx.x & 63;
  int token = blockIdx.x * 4 + (threadIdx.x >> 6);
  const float* xr = x + (size_t)token * DIMD;
  float s0 = 0.f, s1 = 0.f, s2 = 0.f, s3 = 0.f;
  for (int i = lane; i < DIMD; i += 64) {
    float xv = xr[i];
    float4 g = *(const float4*)(gw + i * 4);
    s0 = fmaf(xv, g.x, s0); s1 = fmaf(xv, g.y, s1);
    s2 = fmaf(xv, g.z, s2); s3 = fmaf(xv, g.w, s3);
  }
#pragma unroll
  for (int m = 32; m >= 1; m >>= 1) {
    s0 += __shfl_xor(s0, m); s1 += __shfl_xor(s1, m);
    s2 += __shfl_xor(s2, m); s3 += __shfl_xor(s3, m);
  }
  if (lane == 0) {
    float sc[4] = { s0 + gb[0], s1 + gb[1], s2 + gb[2], s3 + gb[3] };
    float mx = fmaxf(fmaxf(sc[0], sc[1]), fmaxf(sc[2], sc[3]));
    float p[4]; float z = 0.f;
#pragma unroll
    for (int e = 0; e < 4; ++e) { p[e] = __expf(sc[e] - mx); z += p[e]; }
#pragma unroll
    for (int e = 0; e < 4; ++e) p[e] /= z;
    int i1 = 0;
#pragma unroll
    for (int e = 1; e < 4; ++e) if (p[e] > p[i1]) i1 = e;
    int i2 = -1;
#pragma unroll
    for (int e = 0; e < 4; ++e) if (e != i1 && (i2 < 0 || p[e] > p[i2])) i2 = e;
    float denom = p[i1] + p[i2] + 1e-9f;
    float w[4] = {0.f, 0.f, 0.f, 0.f};
    w[i1] = p[i1] / denom;
    w[i2] = p[i2] / denom;
    float4 wv = { w[0], w[1], w[2], w[3] };
    *(float4*)(wgt + token * 4) = wv;
    int a = i1 < i2 ? i1 : i2, b = i1 < i2 ? i2 : i1;
    pid[token] = (unsigned char)(3 * a - (a * (a - 1)) / 2 + (b - a - 1));
  }
}

// ---------------- bucket tokens by expert pair ----------------
__global__ __launch_bounds__(256) void bucket_kernel(
    const unsigned char* __restrict__ pid, int* __restrict__ idx,
    int* __restrict__ cnt) {
  int t = blockIdx.x * 256 + threadIdx.x;
  int lane = threadIdx.x & 63;
  int p = pid[t];
#pragma unroll
  for (int q = 0; q < NPAIR; ++q) {
    unsigned long long mask = __ballot(p == q);
    if (mask) {
      int lead = __ffsll((long long)mask) - 1;
      int base = 0;
      if (lane == lead) base = atomicAdd(&cnt[q], (int)__popcll(mask));
      base = __shfl(base, lead);
      if (p == q) {
        int rank = (int)__popcll(mask & ((1ull << lane) - 1ull));
        idx[q * TOKENS + base + rank] = t;
      }
    }
  }
}

// ---------------- sparse fused MoE FFN ----------------
// grid 6*512 wgs of 256 thr (4 waves); each active wg: 64 gathered tokens,
// its pair's 2 experts. Per wave: 16 tokens, full 384-dim out in regs.
#define LDX(ks) (*(const bf16x8*)((const char*)xs + \
    (((xrow * DIMD + 32 * (ks) + 8 * lhi) * 2) ^ ((xrow & 7) << 4))))
#define LDW1(nf, ks) (*(const bf16x8*)(w1b + (size_t)(16 * (nf)) * DIMD + 32 * (ks)))
#define LDW2(nt, w4) (*(const bf16x8*)(w2b + (size_t)(16 * (nt)) * HID + 32 * (w4)))

__global__ __launch_bounds__(256, 2) void moe_ffn_sparse(
    const float* __restrict__ x, const unsigned short* __restrict__ w1t,
    const unsigned short* __restrict__ w2t, const float* __restrict__ b1,
    const float* __restrict__ b2, const float* __restrict__ wgt,
    const int* __restrict__ idx, const int* __restrict__ cnt,
    float* __restrict__ out) {
  __shared__ unsigned short xs[BM * DIMD];  // 48 KiB, XOR-swizzled rows
  __shared__ int tk[BM];
  const int bid = blockIdx.x;
  const int pr = bid >> 9;
  const int tile = bid & (TILES_PER_PAIR - 1);
  const int n = cnt[pr];
  if (tile * BM >= n) return;
  const int te1[NPAIR] = {0, 0, 0, 1, 1, 2};
  const int te2[NPAIR] = {1, 2, 3, 2, 3, 3};
  const int eA = te1[pr], eB = te2[pr];
  const int tid = threadIdx.x;
  const int wid = tid >> 6, lane = tid & 63;
  const int lhi = lane >> 4, llo = lane & 15;

  if (tid < BM) {
    int sl = tile * BM + tid;
    tk[tid] = idx[pr * TOKENS + (sl < n ? sl : n - 1)];
  }
  __syncthreads();
#pragma unroll
  for (int i = 0; i < 24; ++i) {  // 64 rows * 96 float4 / 256 thr
    int i4 = i * 256 + tid;
    int m = i4 / 96, kq = i4 - m * 96;
    const float4 v = *(const float4*)(x + (size_t)tk[m] * DIMD + kq * 4);
    ushort4 h4;
    h4.x = f2bf(v.x); h4.y = f2bf(v.y); h4.z = f2bf(v.z); h4.w = f2bf(v.w);
    int byte = ((m * DIMD + kq * 4) * 2) ^ ((m & 7) << 4);
    *(ushort4*)((char*)xs + byte) = h4;
  }
  __syncthreads();

  const int xrow = 16 * wid + llo;          // this lane's token slot in tile
  const int myslot = tile * BM + xrow;
  const int mytok = tk[xrow];
  const bool valid = myslot < n;

  f32x4 acc2[24] = {};  // out^T: dim = 16*nt + 4*lhi + r, token col = llo

#pragma unroll
  for (int ee = 0; ee < 2; ++ee) {
    const int e = ee ? eB : eA;
    const float wl = wgt[mytok * 4 + e];
    const unsigned short* w1e = w1t + (size_t)e * HID * DIMD;
    const unsigned short* w2e = w2t + (size_t)e * DIMD * HID;
    const float* b1e = b1 + e * HID;
    for (int hc = 0; hc < HID / BH; ++hc) {
      const int hh = hc * BH;
      // ---- GEMM1 (swapped): Ht[hid 128][tok 16] = w1_chunk @ x^T ----
      const unsigned short* w1b = w1e + (size_t)(hh + llo) * DIMD + 8 * lhi;
      f32x4 acc1[8] = {};
      bf16x8 wb[2][4];
      bf16x8 xb[2];
      xb[0] = LDX(0);
#pragma unroll
      for (int q = 0; q < 4; ++q) wb[0][q] = LDW1(q, 0);
#pragma unroll
      for (int s = 0; s < 24; ++s) {  // (ks 0..11) x (half 0..1)
        const int ks = s >> 1, half = s & 1;
        if (s < 23) {
          const int sn = s + 1, ksn = sn >> 1, hn = sn & 1;
#pragma unroll
          for (int q = 0; q < 4; ++q) wb[sn & 1][q] = LDW1(4 * hn + q, ksn);
          if (hn == 0) xb[ksn & 1] = LDX(ksn);
        }
#pragma unroll
        for (int q = 0; q < 4; ++q)
          acc1[4 * half + q] = __builtin_amdgcn_mfma_f32_16x16x32_bf16(
              wb[s & 1][q], xb[ks & 1], acc1[4 * half + q], 0, 0, 0);
      }
      // ---- gelu+scale, pack to bf16, in-register relayout via shfl ----
      // lane holds H[tok=llo][hid = hh+16*nf+4*lhi+r]; GEMM2 B-frag needs
      // H[tok=llo][hid = hh+32*w4+8*lhi+j].  reg m of window w4 comes from
      // P(f=lhi>>1, p=m&1) at source lane 32*(lhi&1)+16*(m>>1)+llo.
      bf16x8 pa[4];
#pragma unroll
      for (int w4 = 0; w4 < 4; ++w4) {
        unsigned P[2][2];
#pragma unroll
        for (int f = 0; f < 2; ++f) {
          const int nf = 2 * w4 + f;
          const float4 bq = *(const float4*)(b1e + hh + 16 * nf + 4 * lhi);
          P[f][0] = pk2(gelu_f(acc1[nf][0] + bq.x) * wl,
                        gelu_f(acc1[nf][1] + bq.y) * wl);
          P[f][1] = pk2(gelu_f(acc1[nf][2] + bq.z) * wl,
                        gelu_f(acc1[nf][3] + bq.w) * wl);
        }
        const int sA = 32 * (lhi & 1) + llo;
        const int sB = sA + 16;
        unsigned a00 = (unsigned)__shfl((int)P[0][0], sA);
        unsigned a10 = (unsigned)__shfl((int)P[1][0], sA);
        unsigned a01 = (unsigned)__shfl((int)P[0][1], sA);
        unsigned a11 = (unsigned)__shfl((int)P[1][1], sA);
        unsigned b00 = (unsigned)__shfl((int)P[0][0], sB);
        unsigned b10 = (unsigned)__shfl((int)P[1][0], sB);
        unsigned b01 = (unsigned)__shfl((int)P[0][1], sB);
        unsigned b11 = (unsigned)__shfl((int)P[1][1], sB);
        const bool hif = lhi >= 2;
        u32x4 mm;
        mm.x = hif ? a10 : a00;
        mm.y = hif ? a11 : a01;
        mm.z = hif ? b10 : b00;
        mm.w = hif ? b11 : b01;
        pa[w4] = __builtin_bit_cast(bf16x8, mm);
      }
      // ---- GEMM2 (out^T): acc2 += w2^T_chunk @ Ht ----
      const unsigned short* w2b = w2e + (size_t)llo * HID + hh + 8 * lhi;
      bf16x8 vb[2][4];
#pragma unroll
      for (int q = 0; q < 4; ++q) vb[0][q] = LDW2(q, 0);
#pragma unroll
      for (int s = 0; s < 24; ++s) {  // (w4 0..3) x (ntg 0..5)
        const int w4 = s / 6, g = s % 6;
        if (s < 23) {
          const int sn = s + 1, w4n = sn / 6, gn = sn % 6;
#pragma unroll
          for (int q = 0; q < 4; ++q) vb[sn & 1][q] = LDW2(4 * gn + q, w4n);
        }
#pragma unroll
        for (int q = 0; q < 4; ++q)
          acc2[4 * g + q] = __builtin_amdgcn_mfma_f32_16x16x32_bf16(
              vb[s & 1][q], pa[w4], acc2[4 * g + q], 0, 0, 0);
      }
    }  // hc
  }  // ee

  // ---- epilogue: bias mix of the 2 selected experts, float4 stores ----
  if (valid) {
    const float weA = wgt[mytok * 4 + eA];
    const float weB = wgt[mytok * 4 + eB];
    const float* b2A = b2 + eA * DIMD;
    const float* b2B = b2 + eB * DIMD;
    float* orow = out + (size_t)mytok * DIMD;
#pragma unroll
    for (int nt = 0; nt < 24; ++nt) {
      const int d0 = 16 * nt + 4 * lhi;
      const float4 bA = *(const float4*)(b2A + d0);
      const float4 bB = *(const float4*)(b2B + d0);
      float4 o;
      o.x = acc2[nt][0] + weA * bA.x + weB * bB.x;
      o.y = acc2[nt][1] + weA * bA.y + weB * bB.y;
      o.z = acc2[nt][2] + weA * bA.z + weB * bB.z;
      o.w = acc2[nt][3] + weA * bA.w + weB * bB.w;
      *(float4*)(orow + d0) = o;
    }
  }
}

extern "C" void kernel_launch(void* const* d_in, const int* in_sizes, int n_in,
                              void* d_out, int out_size, void* d_ws, size_t ws_size,
                              hipStream_t stream) {
  (void)in_sizes; (void)n_in; (void)out_size; (void)ws_size;
  const float* x  = (const float*)d_in[0];
  const float* gw = (const float*)d_in[1];
  const float* gb = (const float*)d_in[2];
  const float* w1 = (const float*)d_in[3];
  const float* b1 = (const float*)d_in[4];
  const float* w2 = (const float*)d_in[5];
  const float* b2 = (const float*)d_in[6];
  float* out = (float*)d_out;

  // ws layout (bytes):
  //  w1t bf16 [4][1536][384]            @ 0         (4,718,592)
  //  w2t bf16 [4][384][1536]            @ 4,718,592 (4,718,592)
  //  wgt f32  [32768][4]                @ 9,437,184 (524,288)
  //  idx i32  [6][32768]                @ 9,961,472 (786,432)
  //  cnt i32  [8]                       @ 10,747,904 (32)
  //  pid u8   [32768]                   @ 10,747,936 (32,768)
  unsigned short* w1t = (unsigned short*)d_ws;
  unsigned short* w2t = w1t + (size_t)NE * HID * DIMD;
  float* wgt = (float*)((char*)d_ws + 9437184);
  int* idx = (int*)((char*)d_ws + 9961472);
  int* cnt = (int*)((char*)d_ws + 10747904);
  unsigned char* pid = (unsigned char*)((char*)d_ws + 10747936);

  transpose_cvt_kernel<<<dim3(HID / 32, DIMD / 32, NE), dim3(32, 8), 0, stream>>>(
      w1, w1t, DIMD, HID);
  transpose_cvt_kernel<<<dim3(DIMD / 32, HID / 32, NE), dim3(32, 8), 0, stream>>>(
      w2, w2t, HID, DIMD);
  zero_cnt_kernel<<<1, 64, 0, stream>>>(cnt);
  gate_kernel<<<TOKENS / 4, 256, 0, stream>>>(x, gw, gb, wgt, pid);
  bucket_kernel<<<TOKENS / 256, 256, 0, stream>>>(pid, idx, cnt);
  moe_ffn_sparse<<<NPAIR * TILES_PER_PAIR, 256, 0, stream>>>(
      x, w1t, w2t, b1, b2, wgt, idx, cnt, out);
}

// Round 5
// 812.778 us; speedup vs baseline: 2.7364x; 2.7364x over previous
//
#include <hip/hip_runtime.h>

#define TOKENS 32768
#define DIMD 384
#define HID 1536
#define NE 4
#define NPAIR 6
#define BM 64
#define BH 128
#define NCH (HID / BH)   // 12
#define TPP 512          // tile slots per pair

typedef __bf16 bf16;
typedef bf16 bf16x8 __attribute__((ext_vector_type(8)));
typedef float f32x4 __attribute__((ext_vector_type(4)));

__device__ __forceinline__ unsigned short f2bf(float f) {
  unsigned u = __builtin_bit_cast(unsigned, f);
  u += 0x7fffu + ((u >> 16) & 1u);
  return (unsigned short)(u >> 16);
}
// tanh-form gelu, max |err| vs erf-gelu ~4e-4 (threshold 5.7e-2)
__device__ __forceinline__ float gelu_f(float v) {
  float u2 = 1.5957691216057308f * v * (1.0f + 0.044715f * v * v);
  return v / (1.0f + __expf(-u2));
}

// ---------------- transpose + fp32->bf16 convert ----------------
__global__ __launch_bounds__(256) void transpose_cvt_kernel(
    const float* __restrict__ src, unsigned short* __restrict__ dst,
    int R, int C) {
  __shared__ float tile[32][33];
  int e = blockIdx.z;
  const float* s = src + (size_t)e * R * C;
  unsigned short* d = dst + (size_t)e * R * C;
  int c0 = blockIdx.x * 32, r0 = blockIdx.y * 32;
  int tx = threadIdx.x, ty = threadIdx.y;  // (32, 8)
#pragma unroll
  for (int i = 0; i < 32; i += 8)
    tile[ty + i][tx] = s[(size_t)(r0 + ty + i) * C + (c0 + tx)];
  __syncthreads();
#pragma unroll
  for (int i = 0; i < 32; i += 8)
    d[(size_t)(c0 + ty + i) * R + (r0 + tx)] = f2bf(tile[tx][ty + i]);
}

// ---------------- zero counters ----------------
__global__ void zero_cnt_kernel(int* cnt) {
  if (threadIdx.x < 8) cnt[threadIdx.x] = 0;
}

// ---------------- gating: softmax, top-2, renorm, pair-id ----------------
__global__ __launch_bounds__(256) void gate_kernel(
    const float* __restrict__ x, const float* __restrict__ gw,
    const float* __restrict__ gb, float* __restrict__ wgt,
    unsigned char* __restrict__ pid) {
  int lane = threadIdx.x & 63;
  int token = blockIdx.x * 4 + (threadIdx.x >> 6);
  const float* xr = x + (size_t)token * DIMD;
  float s0 = 0.f, s1 = 0.f, s2 = 0.f, s3 = 0.f;
  for (int i = lane; i < DIMD; i += 64) {
    float xv = xr[i];
    float4 g = *(const float4*)(gw + i * 4);
    s0 = fmaf(xv, g.x, s0); s1 = fmaf(xv, g.y, s1);
    s2 = fmaf(xv, g.z, s2); s3 = fmaf(xv, g.w, s3);
  }
#pragma unroll
  for (int m = 32; m >= 1; m >>= 1) {
    s0 += __shfl_xor(s0, m); s1 += __shfl_xor(s1, m);
    s2 += __shfl_xor(s2, m); s3 += __shfl_xor(s3, m);
  }
  if (lane == 0) {
    float sc[4] = { s0 + gb[0], s1 + gb[1], s2 + gb[2], s3 + gb[3] };
    float mx = fmaxf(fmaxf(sc[0], sc[1]), fmaxf(sc[2], sc[3]));
    float p[4]; float z = 0.f;
#pragma unroll
    for (int e = 0; e < 4; ++e) { p[e] = __expf(sc[e] - mx); z += p[e]; }
#pragma unroll
    for (int e = 0; e < 4; ++e) p[e] /= z;
    int i1 = 0;
#pragma unroll
    for (int e = 1; e < 4; ++e) if (p[e] > p[i1]) i1 = e;
    int i2 = -1;
#pragma unroll
    for (int e = 0; e < 4; ++e) if (e != i1 && (i2 < 0 || p[e] > p[i2])) i2 = e;
    float denom = p[i1] + p[i2] + 1e-9f;
    float w[4] = {0.f, 0.f, 0.f, 0.f};
    w[i1] = p[i1] / denom;
    w[i2] = p[i2] / denom;
    float4 wv = { w[0], w[1], w[2], w[3] };
    *(float4*)(wgt + token * 4) = wv;
    int a = i1 < i2 ? i1 : i2, b = i1 < i2 ? i2 : i1;
    pid[token] = (unsigned char)(3 * a - (a * (a - 1)) / 2 + (b - a - 1));
  }
}

// ---------------- bucket tokens by expert pair ----------------
__global__ __launch_bounds__(256) void bucket_kernel(
    const unsigned char* __restrict__ pid, int* __restrict__ idx,
    int* __restrict__ cnt) {
  int t = blockIdx.x * 256 + threadIdx.x;
  int lane = threadIdx.x & 63;
  int p = pid[t];
#pragma unroll
  for (int q = 0; q < NPAIR; ++q) {
    unsigned long long mask = __ballot(p == q);
    if (mask) {
      int lead = __ffsll((long long)mask) - 1;
      int base = 0;
      if (lane == lead) base = atomicAdd(&cnt[q], (int)__popcll(mask));
      base = __shfl(base, lead);
      if (p == q) {
        int rank = (int)__popcll(mask & ((1ull << lane) - 1ull));
        idx[q * TOKENS + base + rank] = t;
      }
    }
  }
}

// ---------------- sparse fused MoE FFN (round-1 dataflow + prefetch) -------
// 4 waves / 256 thr. Tile: 64 gathered tokens x full 384-dim out.
// GEMM1: wave owns 32-hid slice, all 64 M (ratio 8 MFMA : 2 glb loads).
// GEMM2: wave owns 96-dim slice, all 64 M (ratio 24 MFMA : 6 glb loads).
__global__ __launch_bounds__(256, 2) void moe_ffn_sparse(
    const float* __restrict__ x, const unsigned short* __restrict__ w1t,
    const unsigned short* __restrict__ w2t, const float* __restrict__ b1,
    const float* __restrict__ b2, const float* __restrict__ wgt,
    const int* __restrict__ idx, const int* __restrict__ cnt,
    float* __restrict__ out) {
  __shared__ unsigned short xs[BM * DIMD];      // 48 KiB, XOR-swizzled
  __shared__ unsigned short hs[2 * BM * BH];    // 32 KiB, double-buffered
  const int orig = blockIdx.x;
  // chunked XCD swizzle (3072 % 8 == 0 -> bijective)
  const int bid = (orig & 7) * ((NPAIR * TPP) / 8) + (orig >> 3);
  const int pr = bid >> 9;
  const int tile = bid & (TPP - 1);
  const int n = cnt[pr];
  if (tile * BM >= n) return;
  const int te1[NPAIR] = {0, 0, 0, 1, 1, 2};
  const int te2[NPAIR] = {1, 2, 3, 2, 3, 3};
  const int eA = te1[pr], eB = te2[pr];
  const int tid = threadIdx.x;
  const int wid = tid >> 6, lane = tid & 63;
  const int lhi = lane >> 4, llo = lane & 15;
  const int base = pr * TOKENS;
  const int slot0 = tile * BM;

  // stage gathered x tile: fp32 -> bf16, swizzled
#pragma unroll
  for (int i = 0; i < 24; ++i) {
    int i4 = i * 256 + tid;
    int m = i4 / 96, kq = i4 - m * 96;
    int sl = slot0 + m;
    int tok = idx[base + (sl < n ? sl : n - 1)];
    const float4 v = *(const float4*)(x + (size_t)tok * DIMD + kq * 4);
    ushort4 h4;
    h4.x = f2bf(v.x); h4.y = f2bf(v.y); h4.z = f2bf(v.z); h4.w = f2bf(v.w);
    int byte = ((m * DIMD + kq * 4) * 2) ^ ((m & 7) << 4);
    *(ushort4*)((char*)xs + byte) = h4;
  }
  // this lane's 16 token slots (rows m = 16q + 4*lhi + r)
  int tks[16];
#pragma unroll
  for (int q = 0; q < 4; ++q)
#pragma unroll
    for (int r = 0; r < 4; ++r) {
      int sl = slot0 + 16 * q + 4 * lhi + r;
      tks[4 * q + r] = idx[base + (sl < n ? sl : n - 1)];
    }
  __syncthreads();

  f32x4 acc2[4][6] = {};  // [mt][nt]: row tok = 16mt+4lhi+r, col d = 96wid+16nt+llo

#pragma unroll 1
  for (int ee = 0; ee < 2; ++ee) {
    const int e = ee ? eB : eA;
    float wrow[16];
#pragma unroll
    for (int j = 0; j < 16; ++j) wrow[j] = wgt[tks[j] * 4 + e];
    const unsigned short* w1e = w1t + (size_t)e * HID * DIMD;
    const unsigned short* w2e = w2t + (size_t)e * DIMD * HID;

#pragma unroll 1
    for (int hc = 0; hc < NCH; ++hc) {
      unsigned short* hp = hs + ((ee * NCH + hc) & 1) * (BM * BH);
      // ---- GEMM1: all 64 tok x this wave's 32-hid slice, K=384 ----
      const unsigned short* w1b =
          w1e + (size_t)(hc * BH + 32 * wid + llo) * DIMD + 8 * lhi;
      f32x4 acc1[4][2] = {};
      bf16x8 wb[2][2];
#pragma unroll
      for (int s = 0; s < 2; ++s) {
        wb[s][0] = *(const bf16x8*)(w1b + 32 * s);
        wb[s][1] = *(const bf16x8*)(w1b + (size_t)16 * DIMD + 32 * s);
      }
#pragma unroll
      for (int ks = 0; ks < 12; ++ks) {
        bf16x8 a[4];
#pragma unroll
        for (int mi = 0; mi < 4; ++mi) {
          int m = 16 * mi + llo;
          int byte = ((m * DIMD + 32 * ks + 8 * lhi) * 2) ^ ((m & 7) << 4);
          a[mi] = *(const bf16x8*)((const char*)xs + byte);
        }
        bf16x8 c0 = wb[ks & 1][0], c1 = wb[ks & 1][1];
        if (ks < 10) {  // ring prefetch, distance 2
          wb[ks & 1][0] = *(const bf16x8*)(w1b + 32 * (ks + 2));
          wb[ks & 1][1] =
              *(const bf16x8*)(w1b + (size_t)16 * DIMD + 32 * (ks + 2));
        }
#pragma unroll
        for (int mi = 0; mi < 4; ++mi) {
          acc1[mi][0] = __builtin_amdgcn_mfma_f32_16x16x32_bf16(
              a[mi], c0, acc1[mi][0], 0, 0, 0);
          acc1[mi][1] = __builtin_amdgcn_mfma_f32_16x16x32_bf16(
              a[mi], c1, acc1[mi][1], 0, 0, 0);
        }
      }
      // ---- prime GEMM2 weight frags (latency hides under gelu+barrier) ----
      const unsigned short* w2b =
          w2e + (size_t)(96 * wid + llo) * HID + hc * BH + 8 * lhi;
      bf16x8 wv[2][6];
#pragma unroll
      for (int s = 0; s < 2; ++s)
#pragma unroll
        for (int q = 0; q < 6; ++q)
          wv[s][q] = *(const bf16x8*)(w2b + (size_t)(16 * q) * HID + 32 * s);
      // ---- gelu + routing-weight scale -> hs[cur] ----
#pragma unroll
      for (int mi = 0; mi < 4; ++mi)
#pragma unroll
        for (int nf = 0; nf < 2; ++nf) {
          float b1v = b1[e * HID + hc * BH + 32 * wid + 16 * nf + llo];
#pragma unroll
          for (int r = 0; r < 4; ++r) {
            int m = 16 * mi + 4 * lhi + r;
            int k = 32 * wid + 16 * nf + llo;
            float hv = gelu_f(acc1[mi][nf][r] + b1v) * wrow[4 * mi + r];
            int byte = ((m * BH + k) * 2) ^ ((m & 7) << 4);
            *(unsigned short*)((char*)hp + byte) = f2bf(hv);
          }
        }
      __syncthreads();  // one barrier per chunk (dbuf removes the second)
      // ---- GEMM2: acc2 += hs[64][128] @ w2 slice ----
#pragma unroll
      for (int ks2 = 0; ks2 < 4; ++ks2) {
        bf16x8 a2[4];
#pragma unroll
        for (int mt = 0; mt < 4; ++mt) {
          int m = 16 * mt + llo;
          int byte = ((m * BH + 32 * ks2 + 8 * lhi) * 2) ^ ((m & 7) << 4);
          a2[mt] = *(const bf16x8*)((const char*)hp + byte);
        }
        bf16x8 c[6];
#pragma unroll
        for (int q = 0; q < 6; ++q) c[q] = wv[ks2 & 1][q];
        if (ks2 < 2) {  // ring prefetch, distance 2
#pragma unroll
          for (int q = 0; q < 6; ++q)
            wv[ks2 & 1][q] =
                *(const bf16x8*)(w2b + (size_t)(16 * q) * HID + 32 * (ks2 + 2));
        }
#pragma unroll
        for (int nt = 0; nt < 6; ++nt)
#pragma unroll
          for (int mt = 0; mt < 4; ++mt)
            acc2[mt][nt] = __builtin_amdgcn_mfma_f32_16x16x32_bf16(
                a2[mt], c[nt], acc2[mt][nt], 0, 0, 0);
      }
    }  // hc
  }  // ee

  // ---- epilogue: bias mix of the 2 selected experts ----
  float b2A[6], b2B[6];
#pragma unroll
  for (int nt = 0; nt < 6; ++nt) {
    int d = 96 * wid + 16 * nt + llo;
    b2A[nt] = b2[eA * DIMD + d];
    b2B[nt] = b2[eB * DIMD + d];
  }
#pragma unroll
  for (int mt = 0; mt < 4; ++mt)
#pragma unroll
    for (int r = 0; r < 4; ++r) {
      int sl = slot0 + 16 * mt + 4 * lhi + r;
      if (sl < n) {
        int tok = tks[4 * mt + r];
        float wA = wgt[tok * 4 + eA], wB = wgt[tok * 4 + eB];
        float* orow = out + (size_t)tok * DIMD + 96 * wid + llo;
#pragma unroll
        for (int nt = 0; nt < 6; ++nt)
          orow[16 * nt] = acc2[mt][nt][r] + wA * b2A[nt] + wB * b2B[nt];
      }
    }
}

extern "C" void kernel_launch(void* const* d_in, const int* in_sizes, int n_in,
                              void* d_out, int out_size, void* d_ws, size_t ws_size,
                              hipStream_t stream) {
  (void)in_sizes; (void)n_in; (void)out_size; (void)ws_size;
  const float* x  = (const float*)d_in[0];
  const float* gw = (const float*)d_in[1];
  const float* gb = (const float*)d_in[2];
  const float* w1 = (const float*)d_in[3];
  const float* b1 = (const float*)d_in[4];
  const float* w2 = (const float*)d_in[5];
  const float* b2 = (const float*)d_in[6];
  float* out = (float*)d_out;

  // ws layout (bytes):
  //  w1t bf16 [4][1536][384] @ 0          w2t bf16 [4][384][1536] @ 4718592
  //  wgt f32 [32768][4] @ 9437184         idx i32 [6][32768] @ 9961472
  //  cnt i32 [8] @ 10747904               pid u8 [32768] @ 10747936
  unsigned short* w1t = (unsigned short*)d_ws;
  unsigned short* w2t = w1t + (size_t)NE * HID * DIMD;
  float* wgt = (float*)((char*)d_ws + 9437184);
  int* idx = (int*)((char*)d_ws + 9961472);
  int* cnt = (int*)((char*)d_ws + 10747904);
  unsigned char* pid = (unsigned char*)((char*)d_ws + 10747936);

  transpose_cvt_kernel<<<dim3(HID / 32, DIMD / 32, NE), dim3(32, 8), 0, stream>>>(
      w1, w1t, DIMD, HID);
  transpose_cvt_kernel<<<dim3(DIMD / 32, HID / 32, NE), dim3(32, 8), 0, stream>>>(
      w2, w2t, HID, DIMD);
  zero_cnt_kernel<<<1, 64, 0, stream>>>(cnt);
  gate_kernel<<<TOKENS / 4, 256, 0, stream>>>(x, gw, gb, wgt, pid);
  bucket_kernel<<<TOKENS / 256, 256, 0, stream>>>(pid, idx, cnt);
  moe_ffn_sparse<<<NPAIR * TPP, 256, 0, stream>>>(
      x, w1t, w2t, b1, b2, wgt, idx, cnt, out);
}

// Round 6
// 689.124 us; speedup vs baseline: 3.2274x; 1.1794x over previous
//
#include <hip/hip_runtime.h>

#define TOKENS 32768
#define DIMD 384
#define HID 1536
#define NE 4
#define NPAIR 6
#define BM 64
#define BH 128
#define NCH (HID / BH)   // 12
#define GRID2 544        // 8 * 68, >= max active tiles (518)

typedef __bf16 bf16;
typedef bf16 bf16x8 __attribute__((ext_vector_type(8)));
typedef float f32x4 __attribute__((ext_vector_type(4)));

__device__ __forceinline__ unsigned short f2bf(float f) {
  unsigned u = __builtin_bit_cast(unsigned, f);
  u += 0x7fffu + ((u >> 16) & 1u);
  return (unsigned short)(u >> 16);
}
// tanh-form gelu, max |err| vs erf-gelu ~4e-4 (threshold 5.7e-2)
__device__ __forceinline__ float gelu_f(float v) {
  float u2 = 1.5957691216057308f * v * (1.0f + 0.044715f * v * v);
  return v / (1.0f + __expf(-u2));
}

// ---------------- transpose + fp32->bf16 convert ----------------
__global__ __launch_bounds__(256) void transpose_cvt_kernel(
    const float* __restrict__ src, unsigned short* __restrict__ dst,
    int R, int C) {
  __shared__ float tile[32][33];
  int e = blockIdx.z;
  const float* s = src + (size_t)e * R * C;
  unsigned short* d = dst + (size_t)e * R * C;
  int c0 = blockIdx.x * 32, r0 = blockIdx.y * 32;
  int tx = threadIdx.x, ty = threadIdx.y;  // (32, 8)
#pragma unroll
  for (int i = 0; i < 32; i += 8)
    tile[ty + i][tx] = s[(size_t)(r0 + ty + i) * C + (c0 + tx)];
  __syncthreads();
#pragma unroll
  for (int i = 0; i < 32; i += 8)
    d[(size_t)(c0 + ty + i) * R + (r0 + tx)] = f2bf(tile[tx][ty + i]);
}

// ---------------- zero counters ----------------
__global__ void zero_cnt_kernel(int* cnt) {
  if (threadIdx.x < 8) cnt[threadIdx.x] = 0;
}

// ---------------- gating: softmax, top-2, renorm, pair-id ----------------
__global__ __launch_bounds__(256) void gate_kernel(
    const float* __restrict__ x, const float* __restrict__ gw,
    const float* __restrict__ gb, float* __restrict__ wgt,
    unsigned char* __restrict__ pid) {
  int lane = threadIdx.x & 63;
  int token = blockIdx.x * 4 + (threadIdx.x >> 6);
  const float* xr = x + (size_t)token * DIMD;
  float s0 = 0.f, s1 = 0.f, s2 = 0.f, s3 = 0.f;
  for (int i = lane; i < DIMD; i += 64) {
    float xv = xr[i];
    float4 g = *(const float4*)(gw + i * 4);
    s0 = fmaf(xv, g.x, s0); s1 = fmaf(xv, g.y, s1);
    s2 = fmaf(xv, g.z, s2); s3 = fmaf(xv, g.w, s3);
  }
#pragma unroll
  for (int m = 32; m >= 1; m >>= 1) {
    s0 += __shfl_xor(s0, m); s1 += __shfl_xor(s1, m);
    s2 += __shfl_xor(s2, m); s3 += __shfl_xor(s3, m);
  }
  if (lane == 0) {
    float sc[4] = { s0 + gb[0], s1 + gb[1], s2 + gb[2], s3 + gb[3] };
    float mx = fmaxf(fmaxf(sc[0], sc[1]), fmaxf(sc[2], sc[3]));
    float p[4]; float z = 0.f;
#pragma unroll
    for (int e = 0; e < 4; ++e) { p[e] = __expf(sc[e] - mx); z += p[e]; }
#pragma unroll
    for (int e = 0; e < 4; ++e) p[e] /= z;
    int i1 = 0;
#pragma unroll
    for (int e = 1; e < 4; ++e) if (p[e] > p[i1]) i1 = e;
    int i2 = -1;
#pragma unroll
    for (int e = 0; e < 4; ++e) if (e != i1 && (i2 < 0 || p[e] > p[i2])) i2 = e;
    float denom = p[i1] + p[i2] + 1e-9f;
    float w[4] = {0.f, 0.f, 0.f, 0.f};
    w[i1] = p[i1] / denom;
    w[i2] = p[i2] / denom;
    float4 wv = { w[0], w[1], w[2], w[3] };
    *(float4*)(wgt + token * 4) = wv;
    int a = i1 < i2 ? i1 : i2, b = i1 < i2 ? i2 : i1;
    pid[token] = (unsigned char)(3 * a - (a * (a - 1)) / 2 + (b - a - 1));
  }
}

// ---------------- bucket tokens by expert pair ----------------
__global__ __launch_bounds__(256) void bucket_kernel(
    const unsigned char* __restrict__ pid, int* __restrict__ idx,
    int* __restrict__ cnt) {
  int t = blockIdx.x * 256 + threadIdx.x;
  int lane = threadIdx.x & 63;
  int p = pid[t];
#pragma unroll
  for (int q = 0; q < NPAIR; ++q) {
    unsigned long long mask = __ballot(p == q);
    if (mask) {
      int lead = __ffsll((long long)mask) - 1;
      int base = 0;
      if (lane == lead) base = atomicAdd(&cnt[q], (int)__popcll(mask));
      base = __shfl(base, lead);
      if (p == q) {
        int rank = (int)__popcll(mask & ((1ull << lane) - 1ull));
        idx[q * TOKENS + base + rank] = t;
      }
    }
  }
}

// ---------------- plan: compact (pair,tile) list ----------------
__global__ void plan_kernel(const int* __restrict__ cnt, int* __restrict__ map) {
  if (threadIdx.x == 0) {
    int p = 0;
    for (int q = 0; q < NPAIR; ++q) {
      int t = (cnt[q] + BM - 1) / BM;
      for (int i = 0; i < t; ++i) map[p++] = q | (i << 8);
    }
    for (; p < GRID2; ++p) map[p] = -1;
  }
}

// ---------------- sparse fused MoE FFN -------------------------------------
// 4 waves / 256 thr. Tile: 64 gathered tokens x full 384-dim out.
// GEMM1: wave owns 32-hid slice, all 64 M; weight ring depth 4, kept full
// across chunk boundaries. GEMM2: wave owns 96-dim slice; 12 frags primed
// under gelu + ring 2.
__global__ __launch_bounds__(256, 2) void moe_ffn_sparse(
    const float* __restrict__ x, const unsigned short* __restrict__ w1t,
    const unsigned short* __restrict__ w2t, const float* __restrict__ b1,
    const float* __restrict__ b2, const float* __restrict__ wgt,
    const int* __restrict__ idx, const int* __restrict__ cnt,
    const int* __restrict__ map, float* __restrict__ out) {
  __shared__ unsigned short xs[BM * DIMD];      // 48 KiB, XOR-swizzled
  __shared__ unsigned short hs[2 * BM * BH];    // 32 KiB, double-buffered
  __shared__ int tk[BM];
  // chunked XCD swizzle (544 = 8*68, bijective)
  const int bid = (blockIdx.x & 7) * (GRID2 / 8) + (blockIdx.x >> 3);
  const int ent = map[bid];
  if (ent < 0) return;
  const int pr = ent & 255;
  const int tile = ent >> 8;
  const int n = cnt[pr];
  const int te1[NPAIR] = {0, 0, 0, 1, 1, 2};
  const int te2[NPAIR] = {1, 2, 3, 2, 3, 3};
  const int eA = te1[pr], eB = te2[pr];
  const int tid = threadIdx.x;
  const int wid = tid >> 6, lane = tid & 63;
  const int lhi = lane >> 4, llo = lane & 15;
  const int base = pr * TOKENS;
  const int slot0 = tile * BM;

  if (tid < BM) {
    int sl = slot0 + tid;
    tk[tid] = idx[base + (sl < n ? sl : n - 1)];
  }
  __syncthreads();

  // stage gathered x tile: fp32 -> bf16, swizzled
#pragma unroll
  for (int i = 0; i < 24; ++i) {
    int i4 = i * 256 + tid;
    int m = i4 / 96, kq = i4 - m * 96;
    const float4 v = *(const float4*)(x + (size_t)tk[m] * DIMD + kq * 4);
    ushort4 h4;
    h4.x = f2bf(v.x); h4.y = f2bf(v.y); h4.z = f2bf(v.z); h4.w = f2bf(v.w);
    int byte = ((m * DIMD + kq * 4) * 2) ^ ((m & 7) << 4);
    *(ushort4*)((char*)xs + byte) = h4;
  }

  // w1 slice base for a given (expert, chunk)
  auto w1base = [&](int e_, int hc_) {
    return w1t + (size_t)(e_ * HID + hc_ * BH + 32 * wid + llo) * DIMD + 8 * lhi;
  };

  // initial GEMM1 prologue (ks 0..3) — issued before the barrier so the
  // loads fly while other waves finish staging.
  const unsigned short* w1b = w1base(eA, 0);
  bf16x8 wb[4][2];
#pragma unroll
  for (int s = 0; s < 4; ++s) {
    wb[s][0] = *(const bf16x8*)(w1b + 32 * s);
    wb[s][1] = *(const bf16x8*)(w1b + (size_t)16 * DIMD + 32 * s);
  }
  __syncthreads();

  f32x4 acc2[4][6] = {};  // [mt][nt]: row tok = 16mt+4lhi+r, col d = 96wid+16nt+llo

#pragma unroll 1
  for (int ee = 0; ee < 2; ++ee) {
    const int e = ee ? eB : eA;
    float wrow[16];
#pragma unroll
    for (int j = 0; j < 4; ++j)
#pragma unroll
      for (int r = 0; r < 4; ++r)
        wrow[4 * j + r] = wgt[tk[16 * j + 4 * lhi + r] * 4 + e];
    const unsigned short* w2e = w2t + (size_t)e * DIMD * HID;

#pragma unroll 1
    for (int hc = 0; hc < NCH; ++hc) {
      unsigned short* hp = hs + ((ee * NCH + hc) & 1) * (BM * BH);
      const bool has_next = (hc < NCH - 1) || (ee == 0);
      const unsigned short* w1b_next =
          (hc < NCH - 1) ? w1base(e, hc + 1) : w1base(eB, 0);
      // hoist b1 loads (used in gelu; covered by GEMM1)
      float b1v0 = b1[e * HID + hc * BH + 32 * wid + llo];
      float b1v1 = b1[e * HID + hc * BH + 32 * wid + 16 + llo];

      // ---- GEMM1: all 64 tok x this wave's 32-hid slice, K=384 ----
      f32x4 acc1[4][2] = {};
#pragma unroll
      for (int ks = 0; ks < 12; ++ks) {
        bf16x8 a[4];
#pragma unroll
        for (int mi = 0; mi < 4; ++mi) {
          int m = 16 * mi + llo;
          int byte = ((m * DIMD + 32 * ks + 8 * lhi) * 2) ^ ((m & 7) << 4);
          a[mi] = *(const bf16x8*)((const char*)xs + byte);
        }
        bf16x8 c0 = wb[ks & 3][0], c1 = wb[ks & 3][1];
        if (ks < 8) {  // ring prefetch, depth 4
          wb[ks & 3][0] = *(const bf16x8*)(w1b + 32 * (ks + 4));
          wb[ks & 3][1] =
              *(const bf16x8*)(w1b + (size_t)16 * DIMD + 32 * (ks + 4));
        }
#pragma unroll
        for (int mi = 0; mi < 4; ++mi) {
          acc1[mi][0] = __builtin_amdgcn_mfma_f32_16x16x32_bf16(
              a[mi], c0, acc1[mi][0], 0, 0, 0);
          acc1[mi][1] = __builtin_amdgcn_mfma_f32_16x16x32_bf16(
              a[mi], c1, acc1[mi][1], 0, 0, 0);
        }
      }
      // ---- prime GEMM2 weight frags (latency hides under gelu) ----
      const unsigned short* w2b =
          w2e + (size_t)(96 * wid + llo) * HID + hc * BH + 8 * lhi;
      bf16x8 wv[2][6];
#pragma unroll
      for (int s = 0; s < 2; ++s)
#pragma unroll
        for (int q = 0; q < 6; ++q)
          wv[s][q] = *(const bf16x8*)(w2b + (size_t)(16 * q) * HID + 32 * s);
      // ---- gelu + routing-weight scale -> hs[cur] ----
#pragma unroll
      for (int mi = 0; mi < 4; ++mi)
#pragma unroll
        for (int nf = 0; nf < 2; ++nf) {
          float b1v = nf ? b1v1 : b1v0;
#pragma unroll
          for (int r = 0; r < 4; ++r) {
            int m = 16 * mi + 4 * lhi + r;
            int k = 32 * wid + 16 * nf + llo;
            float hv = gelu_f(acc1[mi][nf][r] + b1v) * wrow[4 * mi + r];
            int byte = ((m * BH + k) * 2) ^ ((m & 7) << 4);
            *(unsigned short*)((char*)hp + byte) = f2bf(hv);
          }
        }
      // ---- next chunk's GEMM1 prologue: lands under barrier + GEMM2 ----
      if (has_next) {
#pragma unroll
        for (int s = 0; s < 4; ++s) {
          wb[s][0] = *(const bf16x8*)(w1b_next + 32 * s);
          wb[s][1] = *(const bf16x8*)(w1b_next + (size_t)16 * DIMD + 32 * s);
        }
      }
      __syncthreads();  // one barrier per chunk (dbuf removes the second)
      // ---- GEMM2: acc2 += hs[64][128] @ w2 slice ----
#pragma unroll
      for (int ks2 = 0; ks2 < 4; ++ks2) {
        bf16x8 a2[4];
#pragma unroll
        for (int mt = 0; mt < 4; ++mt) {
          int m = 16 * mt + llo;
          int byte = ((m * BH + 32 * ks2 + 8 * lhi) * 2) ^ ((m & 7) << 4);
          a2[mt] = *(const bf16x8*)((const char*)hp + byte);
        }
        bf16x8 c[6];
#pragma unroll
        for (int q = 0; q < 6; ++q) c[q] = wv[ks2 & 1][q];
        if (ks2 < 2) {  // ring prefetch, distance 2
#pragma unroll
          for (int q = 0; q < 6; ++q)
            wv[ks2 & 1][q] =
                *(const bf16x8*)(w2b + (size_t)(16 * q) * HID + 32 * (ks2 + 2));
        }
#pragma unroll
        for (int nt = 0; nt < 6; ++nt)
#pragma unroll
          for (int mt = 0; mt < 4; ++mt)
            acc2[mt][nt] = __builtin_amdgcn_mfma_f32_16x16x32_bf16(
                a2[mt], c[nt], acc2[mt][nt], 0, 0, 0);
      }
      w1b = w1b_next;
    }  // hc
  }  // ee

  // ---- epilogue: bias mix of the 2 selected experts ----
  float b2A[6], b2B[6];
#pragma unroll
  for (int nt = 0; nt < 6; ++nt) {
    int d = 96 * wid + 16 * nt + llo;
    b2A[nt] = b2[eA * DIMD + d];
    b2B[nt] = b2[eB * DIMD + d];
  }
#pragma unroll
  for (int mt = 0; mt < 4; ++mt)
#pragma unroll
    for (int r = 0; r < 4; ++r) {
      int sl = slot0 + 16 * mt + 4 * lhi + r;
      if (sl < n) {
        int tok = tk[16 * mt + 4 * lhi + r];
        float wA = wgt[tok * 4 + eA], wB = wgt[tok * 4 + eB];
        float* orow = out + (size_t)tok * DIMD + 96 * wid + llo;
#pragma unroll
        for (int nt = 0; nt < 6; ++nt)
          orow[16 * nt] = acc2[mt][nt][r] + wA * b2A[nt] + wB * b2B[nt];
      }
    }
}

extern "C" void kernel_launch(void* const* d_in, const int* in_sizes, int n_in,
                              void* d_out, int out_size, void* d_ws, size_t ws_size,
                              hipStream_t stream) {
  (void)in_sizes; (void)n_in; (void)out_size; (void)ws_size;
  const float* x  = (const float*)d_in[0];
  const float* gw = (const float*)d_in[1];
  const float* gb = (const float*)d_in[2];
  const float* w1 = (const float*)d_in[3];
  const float* b1 = (const float*)d_in[4];
  const float* w2 = (const float*)d_in[5];
  const float* b2 = (const float*)d_in[6];
  float* out = (float*)d_out;

  // ws layout (bytes):
  //  w1t bf16 [4][1536][384] @ 0          w2t bf16 [4][384][1536] @ 4718592
  //  wgt f32 [32768][4] @ 9437184         idx i32 [6][32768] @ 9961472
  //  cnt i32 [8] @ 10747904               pid u8 [32768] @ 10747936
  //  map i32 [544] @ 10780704
  unsigned short* w1t = (unsigned short*)d_ws;
  unsigned short* w2t = w1t + (size_t)NE * HID * DIMD;
  float* wgt = (float*)((char*)d_ws + 9437184);
  int* idx = (int*)((char*)d_ws + 9961472);
  int* cnt = (int*)((char*)d_ws + 10747904);
  unsigned char* pid = (unsigned char*)((char*)d_ws + 10747936);
  int* map = (int*)((char*)d_ws + 10780704);

  transpose_cvt_kernel<<<dim3(HID / 32, DIMD / 32, NE), dim3(32, 8), 0, stream>>>(
      w1, w1t, DIMD, HID);
  transpose_cvt_kernel<<<dim3(DIMD / 32, HID / 32, NE), dim3(32, 8), 0, stream>>>(
      w2, w2t, HID, DIMD);
  zero_cnt_kernel<<<1, 64, 0, stream>>>(cnt);
  gate_kernel<<<TOKENS / 4, 256, 0, stream>>>(x, gw, gb, wgt, pid);
  bucket_kernel<<<TOKENS / 256, 256, 0, stream>>>(pid, idx, cnt);
  plan_kernel<<<1, 64, 0, stream>>>(cnt, map);
  moe_ffn_sparse<<<GRID2, 256, 0, stream>>>(
      x, w1t, w2t, b1, b2, wgt, idx, cnt, map, out);
}